// Round 18
// baseline (188.724 us; speedup 1.0000x reference)
//
#include <hip/hip_runtime.h>

#define NFEAT 512
#define HID 16
#define NCLS 40
#define BROWS 256        // rows per bucket
#define BCAP 16384       // fixed slots per bucket (mean fill 8184, 20+ sigma headroom)
#define PAIRS_BLOCKS 512 // MUST stay 512: fewer blocks -> per-block pairs time exceeds
                         // gemm's window and becomes the fused critical path (R10 lesson)

typedef unsigned int uint32;
typedef float f4 __attribute__((ext_vector_type(4)));

__device__ __forceinline__ uint32 f2bf(float f) {   // round-to-nearest-even bf16
    uint32 u = __float_as_uint(f);
    return (u + 0x7FFFu + ((u >> 16) & 1u)) >> 16;
}
__device__ __forceinline__ float bf2f(uint32 h) {
    return __uint_as_float(h << 16);
}

// ---------------- fused: pairs binning (blocks 0..511) || layer-1 GEMM (rest) ------
// pairs: int4 edge loads, packed (r&255)<<17|c into fixed bucket regions.
// gemm : h1 = bf16( x @ W1 )  UNSCALED (dinv not yet known; k_csrs scales in-place).
__global__ __launch_bounds__(256, 4) void k_fused1(const float* __restrict__ x,
                                                   const float* __restrict__ W,
                                                   uint32* __restrict__ g1, int n,
                                                   const int* __restrict__ row,
                                                   const int* __restrict__ col,
                                                   int* __restrict__ bcur,
                                                   uint32* __restrict__ pairs,
                                                   int E, int nb) {
    __shared__ float smem[8704];   // gemm: padded W1 (34KB); pairs: lhist+lbase (4KB)
    const int tid = threadIdx.x;

    if (blockIdx.x < PAIRS_BLOCKS) {
        int* lhist = (int*)smem;
        int* lbase = (int*)smem + 512;
        const int E4 = E >> 2;
        const int chunk4 = (E4 + PAIRS_BLOCKS - 1) / PAIRS_BLOCKS;
        const int s4 = blockIdx.x * chunk4;
        const int e4 = min(s4 + chunk4, E4);
        const int4* rp = reinterpret_cast<const int4*>(row);
        const int4* cp = reinterpret_cast<const int4*>(col);

        for (int b = tid; b < nb; b += 256) lhist[b] = 0;
        __syncthreads();
        for (int i4 = s4 + tid; i4 < e4; i4 += 256) {
            int4 r4 = rp[i4];
            atomicAdd(&lhist[r4.x >> 8], 1);
            atomicAdd(&lhist[r4.y >> 8], 1);
            atomicAdd(&lhist[r4.z >> 8], 1);
            atomicAdd(&lhist[r4.w >> 8], 1);
        }
        if (blockIdx.x == PAIRS_BLOCKS - 1) {
            for (int i = E4 * 4 + tid; i < E; i += 256)
                atomicAdd(&lhist[row[i] >> 8], 1);
        }
        __syncthreads();
        for (int b = tid; b < nb; b += 256) {
            int h = lhist[b];
            lbase[b] = h ? atomicAdd(&bcur[b], h) : 0;
            lhist[b] = 0;   // reuse as local cursor
        }
        __syncthreads();
        for (int i4 = s4 + tid; i4 < e4; i4 += 256) {
            int4 r4 = rp[i4];
            int4 c4 = cp[i4];
#pragma unroll
            for (int u = 0; u < 4; u++) {
                int r = (&r4.x)[u], c = (&c4.x)[u];
                int b = r >> 8;
                int off = lbase[b] + atomicAdd(&lhist[b], 1);
                if (off < BCAP)
                    pairs[(size_t)b * BCAP + off] = ((uint32)(r & 255) << 17) | (uint32)c;
            }
        }
        if (blockIdx.x == PAIRS_BLOCKS - 1) {
            for (int i = E4 * 4 + tid; i < E; i += 256) {
                int r = row[i], c = col[i];
                int b = r >> 8;
                int off = lbase[b] + atomicAdd(&lhist[b], 1);
                if (off < BCAP)
                    pairs[(size_t)b * BCAP + off] = ((uint32)(r & 255) << 17) | (uint32)c;
            }
        }
        return;
    }

    // ---- gemm branch (2 rows/thread, depth-2 prefetch, padded W-LDS; UNSCALED out) ----
    float* Wl = smem;
    const int ks = tid & 7;       // k-slice
    const int g  = tid >> 3;      // row-group 0..31

#pragma unroll
    for (int i = 0; i < 8; i++) {
        int fidx = tid + i * 256;
        int k = fidx >> 2, j4 = fidx & 3;
        float4 v = reinterpret_cast<const float4*>(W)[fidx];
        *reinterpret_cast<float4*>(&Wl[k * 16 + (k >> 2) * 4 + j4 * 4]) = v;
    }
    __syncthreads();

    const int rbase = (blockIdx.x - PAIRS_BLOCKS) * 64 + g * 2;
    const int r0 = min(rbase, n - 1);       // clamp: OOB rows read row n-1, writes guarded
    const int r1 = min(rbase + 1, n - 1);
    const f4* xq0 = reinterpret_cast<const f4*>(x + (size_t)r0 * NFEAT);
    const f4* xq1 = reinterpret_cast<const f4*>(x + (size_t)r1 * NFEAT);

    float acc[2][16];
#pragma unroll
    for (int rr = 0; rr < 2; rr++)
#pragma unroll
        for (int j = 0; j < 16; j++) acc[rr][j] = 0.f;

    f4 xv[2], xn1[2], xn2[2];
    xv[0]  = __builtin_nontemporal_load(&xq0[ks]);            // c=0
    xv[1]  = __builtin_nontemporal_load(&xq1[ks]);
    xn1[0] = __builtin_nontemporal_load(&xq0[8 + ks]);        // c=1
    xn1[1] = __builtin_nontemporal_load(&xq1[8 + ks]);

    for (int c = 0; c < 16; c++) {
        if (c < 14) {   // prefetch c+2 (two c-iters of latency cover)
            xn2[0] = __builtin_nontemporal_load(&xq0[(c + 2) * 8 + ks]);
            xn2[1] = __builtin_nontemporal_load(&xq1[(c + 2) * 8 + ks]);
        }
#pragma unroll
        for (int m = 0; m < 4; m++) {
            int k = c * 32 + ks * 4 + m;
            const float* wrow = &Wl[k * 16 + (k >> 2) * 4];
            float4 wv[4];
#pragma unroll
            for (int j4 = 0; j4 < 4; j4++)
                wv[j4] = *reinterpret_cast<const float4*>(wrow + j4 * 4);
#pragma unroll
            for (int rr = 0; rr < 2; rr++) {
                float xs = xv[rr][m];
#pragma unroll
                for (int j4 = 0; j4 < 4; j4++) {
                    acc[rr][j4 * 4 + 0] = fmaf(xs, wv[j4].x, acc[rr][j4 * 4 + 0]);
                    acc[rr][j4 * 4 + 1] = fmaf(xs, wv[j4].y, acc[rr][j4 * 4 + 1]);
                    acc[rr][j4 * 4 + 2] = fmaf(xs, wv[j4].z, acc[rr][j4 * 4 + 2]);
                    acc[rr][j4 * 4 + 3] = fmaf(xs, wv[j4].w, acc[rr][j4 * 4 + 3]);
                }
            }
        }
        xv[0] = xn1[0];
        xv[1] = xn1[1];
        xn1[0] = xn2[0];
        xn1[1] = xn2[1];
    }

#pragma unroll
    for (int off = 1; off < 8; off <<= 1)
#pragma unroll
        for (int rr = 0; rr < 2; rr++)
#pragma unroll
            for (int j = 0; j < 16; j++)
                acc[rr][j] += __shfl_xor(acc[rr][j], off, 8);

    if (ks == 0) {
#pragma unroll
        for (int rr = 0; rr < 2; rr++) {
            int r = rbase + rr;
            if (r < n) {
                uint32 us[8];
#pragma unroll
                for (int q = 0; q < 8; q++) {
                    uint32 lo = f2bf(acc[rr][q * 2]);
                    uint32 hi = f2bf(acc[rr][q * 2 + 1]);
                    us[q] = lo | (hi << 16);
                }
                uint4* o = reinterpret_cast<uint4*>(g1 + (size_t)r * 8);
                o[0] = make_uint4(us[0], us[1], us[2], us[3]);
                o[1] = make_uint4(us[4], us[5], us[6], us[7]);
            }
        }
    }
}

// ---------------- per-bucket degree hist -> cnt + dinv ----------------
__global__ __launch_bounds__(256) void k_deg(const int* __restrict__ bcur,
                                             const uint32* __restrict__ pairs,
                                             int* __restrict__ cnt,
                                             float* __restrict__ dinv, int n) {
    __shared__ int lh[BROWS];
    int b = blockIdx.x;
    int bo = b * BCAP;
    int c2 = min(bcur[b], BCAP);
    lh[threadIdx.x] = 0;
    __syncthreads();
    for (int p = bo + (int)threadIdx.x; p < bo + c2; p += 256)
        atomicAdd(&lh[pairs[p] >> 17], 1);
    __syncthreads();
    int i = b * BROWS + threadIdx.x;
    if (i < n) {
        int c = lh[threadIdx.x];
        cnt[i] = c;
        dinv[i] = rsqrtf((float)c + 1.0f);   // +1 = self loop
    }
}

// ---------------- csr scatter + in-place g1 scale (g1 *= dinv per row) -----------
__global__ __launch_bounds__(256) void k_csrs(const int* __restrict__ bcur,
                                              const uint32* __restrict__ pairs,
                                              const int* __restrict__ cnt,
                                              int* __restrict__ csr,
                                              int* __restrict__ start,
                                              int* __restrict__ end,
                                              const float* __restrict__ dinv,
                                              uint32* __restrict__ g1, int n) {
    __shared__ int sm[256];
    __shared__ int lcur[256];
    const int tid = threadIdx.x;
    int b = blockIdx.x;
    int base = b * BROWS;
    int i = base + tid;
    int bo = b * BCAP;
    int cntb = min(bcur[b], BCAP);
    int e2 = bo + cntb;

    int c = (i < n) ? cnt[i] : 0;
    sm[tid] = c;
    __syncthreads();
    for (int off = 1; off < 256; off <<= 1) {
        int t = (tid >= off) ? sm[tid - off] : 0;
        __syncthreads();
        sm[tid] += t;
        __syncthreads();
    }
    int excl = sm[tid] - c;   // exclusive within bucket
    lcur[tid] = excl;
    if (i < n) {
        start[i] = bo + excl;
        end[i]   = bo + excl + c;
    }
    __syncthreads();
    for (int p = bo + tid; p < e2; p += 256) {
        uint32 pk = pairs[p];
        int off = atomicAdd(&lcur[pk >> 17], 1);
        csr[bo + off] = (int)(pk & 0x1FFFFu);
    }
    // in-place prescale of this bucket's g1 rows (one row per thread, coalesced uint4)
    if (i < n) {
        float dr = dinv[i];
        uint4* gp = reinterpret_cast<uint4*>(g1 + (size_t)i * 8);
        uint4 A = gp[0], B = gp[1];
        uint32 w[8] = {A.x, A.y, A.z, A.w, B.x, B.y, B.z, B.w};
#pragma unroll
        for (int q = 0; q < 8; q++) {
            uint32 lo = f2bf(dr * bf2f(w[q] & 0xFFFFu));
            uint32 hi = f2bf(dr * bf2f(w[q] >> 16));
            w[q] = lo | (hi << 16);
        }
        gp[0] = make_uint4(w[0], w[1], w[2], w[3]);
        gp[1] = make_uint4(w[4], w[5], w[6], w[7]);
    }
}

// ---------------- layer 1 aggregation + bias + relu; g2 = bf16(dinv ⊙ relu(z)) ----
__global__ __launch_bounds__(256) void k_agg1(const uint32* __restrict__ g1,
                                              const int* __restrict__ start,
                                              const int* __restrict__ end,
                                              const int* __restrict__ csr,
                                              const float* __restrict__ dinv,
                                              const float* __restrict__ b1,
                                              uint32* __restrict__ g2, int n) {
    int g = threadIdx.x >> 3;
    int l = threadIdx.x & 7;
    int r = blockIdx.x * 32 + g;
    if (r >= n) return;
    int s = start[r], e = end[r];
    float a0 = 0.f, a1 = 0.f;
    int p = s;
    for (; p + 16 <= e; p += 16) {
        int c[16];
#pragma unroll
        for (int u = 0; u < 16; u++) c[u] = csr[p + u];
        uint32 hv[16];
#pragma unroll
        for (int u = 0; u < 16; u++) hv[u] = g1[c[u] * 8 + l];
#pragma unroll
        for (int u = 0; u < 16; u++) {
            a0 += bf2f(hv[u] & 0xFFFFu);
            a1 += bf2f(hv[u] >> 16);
        }
    }
    for (; p + 8 <= e; p += 8) {
        int c[8];
#pragma unroll
        for (int u = 0; u < 8; u++) c[u] = csr[p + u];
        uint32 hv[8];
#pragma unroll
        for (int u = 0; u < 8; u++) hv[u] = g1[c[u] * 8 + l];
#pragma unroll
        for (int u = 0; u < 8; u++) {
            a0 += bf2f(hv[u] & 0xFFFFu);
            a1 += bf2f(hv[u] >> 16);
        }
    }
    for (; p < e; p++) {
        uint32 h = g1[csr[p] * 8 + l];
        a0 += bf2f(h & 0xFFFFu);
        a1 += bf2f(h >> 16);
    }
    uint32 hs = g1[r * 8 + l];
    float dr = dinv[r];
    float z0 = fmaf(dr, a0 + bf2f(hs & 0xFFFFu), b1[2 * l]);
    float z1 = fmaf(dr, a1 + bf2f(hs >> 16), b1[2 * l + 1]);
    g2[r * 8 + l] = f2bf(dr * fmaxf(z0, 0.f)) | (f2bf(dr * fmaxf(z1, 0.f)) << 16);
}

// ---------------- layer 2 fused: aggregate g2, @W2 + b2 + log_softmax ----------
__global__ __launch_bounds__(256) void k_agg2(const uint32* __restrict__ g2,
                                              const int* __restrict__ start,
                                              const int* __restrict__ end,
                                              const int* __restrict__ csr,
                                              const float* __restrict__ dinv,
                                              const float* __restrict__ W2,
                                              const float* __restrict__ b2,
                                              float* __restrict__ out, int n) {
    __shared__ float vsm[32][17];
    int g = threadIdx.x >> 3;
    int l = threadIdx.x & 7;
    int r = blockIdx.x * 32 + g;
    float a0 = 0.f, a1 = 0.f;
    if (r < n) {
        int s = start[r], e = end[r];
        int p = s;
        for (; p + 16 <= e; p += 16) {
            int c[16];
#pragma unroll
            for (int u = 0; u < 16; u++) c[u] = csr[p + u];
            uint32 hv[16];
#pragma unroll
            for (int u = 0; u < 16; u++) hv[u] = g2[c[u] * 8 + l];
#pragma unroll
            for (int u = 0; u < 16; u++) {
                a0 += bf2f(hv[u] & 0xFFFFu);
                a1 += bf2f(hv[u] >> 16);
            }
        }
        for (; p + 8 <= e; p += 8) {
            int c[8];
#pragma unroll
            for (int u = 0; u < 8; u++) c[u] = csr[p + u];
            uint32 hv[8];
#pragma unroll
            for (int u = 0; u < 8; u++) hv[u] = g2[c[u] * 8 + l];
#pragma unroll
            for (int u = 0; u < 8; u++) {
                a0 += bf2f(hv[u] & 0xFFFFu);
                a1 += bf2f(hv[u] >> 16);
            }
        }
        for (; p < e; p++) {
            uint32 h = g2[csr[p] * 8 + l];
            a0 += bf2f(h & 0xFFFFu);
            a1 += bf2f(h >> 16);
        }
        uint32 hs = g2[r * 8 + l];
        float dr = dinv[r];
        a0 = dr * (a0 + bf2f(hs & 0xFFFFu));
        a1 = dr * (a1 + bf2f(hs >> 16));
    }
    vsm[g][2 * l] = a0;
    vsm[g][2 * l + 1] = a1;
    __syncthreads();
    if (r >= n) return;

    float vloc[16];
#pragma unroll
    for (int k = 0; k < 16; k++) vloc[k] = vsm[g][k];

    float z[5];
#pragma unroll
    for (int i = 0; i < 5; i++) z[i] = b2[l + 8 * i];
#pragma unroll
    for (int k = 0; k < 16; k++) {
        float vk = vloc[k];
        const float* wk = W2 + k * NCLS;
#pragma unroll
        for (int i = 0; i < 5; i++) z[i] = fmaf(vk, wk[l + 8 * i], z[i]);
    }
    float m = z[0];
#pragma unroll
    for (int i = 1; i < 5; i++) m = fmaxf(m, z[i]);
#pragma unroll
    for (int off = 1; off < 8; off <<= 1) m = fmaxf(m, __shfl_xor(m, off, 8));
    float ssum = 0.f;
#pragma unroll
    for (int i = 0; i < 5; i++) ssum += __expf(z[i] - m);
#pragma unroll
    for (int off = 1; off < 8; off <<= 1) ssum += __shfl_xor(ssum, off, 8);
    float ls = m + logf(ssum);
    float* o = out + (size_t)r * NCLS;
#pragma unroll
    for (int i = 0; i < 5; i++) o[l + 8 * i] = z[i] - ls;
}

// ---------------- launch ----------------

extern "C" void kernel_launch(void* const* d_in, const int* in_sizes, int n_in,
                              void* d_out, int out_size, void* d_ws, size_t ws_size,
                              hipStream_t stream) {
    const float* x  = (const float*)d_in[0];
    const int*   ei = (const int*)d_in[1];
    const float* W1 = (const float*)d_in[2];
    const float* b1 = (const float*)d_in[3];
    const float* W2 = (const float*)d_in[4];
    const float* b2 = (const float*)d_in[5];

    const int n = in_sizes[0] / NFEAT;   // 100000
    const int E = in_sizes[1] / 2;       // 3200000
    const int* row = ei;
    const int* col = ei + E;
    const int nb = (n + BROWS - 1) / BROWS;   // 391

    char* w = (char*)d_ws;
    auto alloc = [&](size_t bytes) {
        void* p = (void*)w;
        w += (bytes + 255) & ~(size_t)255;
        return p;
    };
    int*    start = (int*)alloc((size_t)n * 4);
    int*    end   = (int*)alloc((size_t)n * 4);
    int*    cnt   = (int*)alloc((size_t)n * 4);
    int*    bcur  = (int*)alloc(2048);
    float*  dinv  = (float*)alloc((size_t)n * 4);
    int*    csr   = (int*)alloc((size_t)nb * BCAP * 4);
    uint32* pairs = (uint32*)alloc((size_t)nb * BCAP * 4);
    uint32* g1    = (uint32*)alloc((size_t)n * HID * 2);
    uint32* g2    = (uint32*)alloc((size_t)n * HID * 2);

    hipMemsetAsync(bcur, 0, 2048, stream);
    k_fused1<<<PAIRS_BLOCKS + (n + 63) / 64, 256, 0, stream>>>(
        x, W1, g1, n, row, col, bcur, pairs, E, nb);
    k_deg<<<nb, 256, 0, stream>>>(bcur, pairs, cnt, dinv, n);
    k_csrs<<<nb, 256, 0, stream>>>(bcur, pairs, cnt, csr, start, end, dinv, g1, n);
    k_agg1<<<(n + 31) / 32, 256, 0, stream>>>(g1, start, end, csr, dinv, b1, g2, n);
    k_agg2<<<(n + 31) / 32, 256, 0, stream>>>(g2, start, end, csr, dinv, W2, b2,
                                              (float*)d_out, n);
}

// Round 19
// 176.073 us; speedup vs baseline: 1.0719x; 1.0719x over previous
//
#include <hip/hip_runtime.h>

#define NFEAT 512
#define HID 16
#define NCLS 40
#define BROWS 256    // rows per bucket
#define BCAP 16384   // fixed slots per bucket (mean fill 8184, 20+ sigma headroom)

typedef unsigned int uint32;
typedef float f4 __attribute__((ext_vector_type(4)));

__device__ __forceinline__ uint32 f2bf(float f) {   // round-to-nearest-even bf16
    uint32 u = __float_as_uint(f);
    return (u + 0x7FFFu + ((u >> 16) & 1u)) >> 16;
}
__device__ __forceinline__ float bf2f(uint32 h) {
    return __uint_as_float(h << 16);
}

// ---------------- single-pass bucket binning: packed (r&255,c), int4 edge loads ----
// 512 blocks (proven best; 1024 halves write-run length, 256 makes pairs critical path)
__global__ __launch_bounds__(256) void k_pairs(const int* __restrict__ row,
                                               const int* __restrict__ col,
                                               int* __restrict__ bcur,
                                               uint32* __restrict__ pairs, int E, int nb) {
    __shared__ int lhist[512];
    __shared__ int lbase[512];
    const int E4 = E >> 2;
    const int chunk4 = (E4 + gridDim.x - 1) / gridDim.x;
    const int s4 = blockIdx.x * chunk4;
    const int e4 = min(s4 + chunk4, E4);
    const int4* rp = reinterpret_cast<const int4*>(row);
    const int4* cp = reinterpret_cast<const int4*>(col);

    for (int b = threadIdx.x; b < nb; b += 256) lhist[b] = 0;
    __syncthreads();
    for (int i4 = s4 + (int)threadIdx.x; i4 < e4; i4 += 256) {
        int4 r4 = rp[i4];
        atomicAdd(&lhist[r4.x >> 8], 1);
        atomicAdd(&lhist[r4.y >> 8], 1);
        atomicAdd(&lhist[r4.z >> 8], 1);
        atomicAdd(&lhist[r4.w >> 8], 1);
    }
    if (blockIdx.x == gridDim.x - 1) {
        for (int i = E4 * 4 + (int)threadIdx.x; i < E; i += 256)
            atomicAdd(&lhist[row[i] >> 8], 1);
    }
    __syncthreads();
    for (int b = threadIdx.x; b < nb; b += 256) {
        int h = lhist[b];
        lbase[b] = h ? atomicAdd(&bcur[b], h) : 0;
        lhist[b] = 0;   // reuse as local cursor
    }
    __syncthreads();
    for (int i4 = s4 + (int)threadIdx.x; i4 < e4; i4 += 256) {
        int4 r4 = rp[i4];
        int4 c4 = cp[i4];
#pragma unroll
        for (int u = 0; u < 4; u++) {
            int r = (&r4.x)[u], c = (&c4.x)[u];
            int b = r >> 8;
            int off = lbase[b] + atomicAdd(&lhist[b], 1);
            if (off < BCAP)
                pairs[(size_t)b * BCAP + off] = ((uint32)(r & 255) << 17) | (uint32)c;
        }
    }
    if (blockIdx.x == gridDim.x - 1) {
        for (int i = E4 * 4 + (int)threadIdx.x; i < E; i += 256) {
            int r = row[i], c = col[i];
            int b = r >> 8;
            int off = lbase[b] + atomicAdd(&lhist[b], 1);
            if (off < BCAP)
                pairs[(size_t)b * BCAP + off] = ((uint32)(r & 255) << 17) | (uint32)c;
        }
    }
}

// ---------------- per-bucket degree hist -> cnt + dinv (enables csr||gemm overlap) ----
__global__ __launch_bounds__(256) void k_deg(const int* __restrict__ bcur,
                                             const uint32* __restrict__ pairs,
                                             int* __restrict__ cnt,
                                             float* __restrict__ dinv, int n) {
    __shared__ int lh[BROWS];
    int b = blockIdx.x;
    int bo = b * BCAP;
    int c2 = min(bcur[b], BCAP);
    lh[threadIdx.x] = 0;
    __syncthreads();
    for (int p = bo + (int)threadIdx.x; p < bo + c2; p += 256)
        atomicAdd(&lh[pairs[p] >> 17], 1);
    __syncthreads();
    int i = b * BROWS + threadIdx.x;
    if (i < n) {
        int c = lh[threadIdx.x];
        cnt[i] = c;
        dinv[i] = rsqrtf((float)c + 1.0f);   // +1 = self loop
    }
}

// ---------------- fused: CSR scatter (blocks 0..nbCsr-1) || layer-1 GEMM (rest) ------
// csr part: scan cnt (coalesced), scatter cols bucket-locally.
// gemm part: g1 = bf16( dinv ⊙ (x @ W1) ); 2 rows/thread, depth-2 prefetch,
// (256,4) -> no spill (R15's (256,8) forced 32 VGPR and spilled: 176->323us).
__global__ __launch_bounds__(256, 4) void k_fused(const int* __restrict__ bcur,
                                                  const uint32* __restrict__ pairs,
                                                  const int* __restrict__ cnt,
                                                  int* __restrict__ csr,
                                                  int* __restrict__ start,
                                                  int* __restrict__ end,
                                                  const float* __restrict__ x,
                                                  const float* __restrict__ W,
                                                  const float* __restrict__ dinv,
                                                  uint32* __restrict__ g1,
                                                  int n, int nbCsr) {
    __shared__ float smem[8704];   // gemm: padded W1 (34KB); csr: sm+lcur (2KB)
    const int tid = threadIdx.x;

    if (blockIdx.x < (uint32)nbCsr) {
        int* sm   = (int*)smem;
        int* lcur = (int*)smem + 256;
        int b = blockIdx.x;
        int base = b * BROWS;
        int i = base + tid;
        int bo = b * BCAP;
        int cntb = min(bcur[b], BCAP);
        int e2 = bo + cntb;

        int c = (i < n) ? cnt[i] : 0;
        sm[tid] = c;
        __syncthreads();
        for (int off = 1; off < 256; off <<= 1) {
            int t = (tid >= off) ? sm[tid - off] : 0;
            __syncthreads();
            sm[tid] += t;
            __syncthreads();
        }
        int excl = sm[tid] - c;   // exclusive within bucket
        lcur[tid] = excl;
        if (i < n) {
            start[i] = bo + excl;
            end[i]   = bo + excl + c;
        }
        __syncthreads();
        for (int p = bo + tid; p < e2; p += 256) {
            uint32 pk = pairs[p];
            int off = atomicAdd(&lcur[pk >> 17], 1);
            csr[bo + off] = (int)(pk & 0x1FFFFu);
        }
        return;
    }

    // ---- gemm branch (2 rows/thread, depth-2 prefetch, padded W-LDS) ----
    float* Wl = smem;
    const int ks = tid & 7;       // k-slice
    const int g  = tid >> 3;      // row-group 0..31

#pragma unroll
    for (int i = 0; i < 8; i++) {
        int fidx = tid + i * 256;
        int k = fidx >> 2, j4 = fidx & 3;
        float4 v = reinterpret_cast<const float4*>(W)[fidx];
        *reinterpret_cast<float4*>(&Wl[k * 16 + (k >> 2) * 4 + j4 * 4]) = v;
    }
    __syncthreads();

    const int rbase = (blockIdx.x - nbCsr) * 64 + g * 2;
    const int r0 = min(rbase, n - 1);       // clamp: OOB rows read row n-1, writes guarded
    const int r1 = min(rbase + 1, n - 1);
    const f4* xq0 = reinterpret_cast<const f4*>(x + (size_t)r0 * NFEAT);
    const f4* xq1 = reinterpret_cast<const f4*>(x + (size_t)r1 * NFEAT);

    float acc[2][16];
#pragma unroll
    for (int rr = 0; rr < 2; rr++)
#pragma unroll
        for (int j = 0; j < 16; j++) acc[rr][j] = 0.f;

    f4 xv[2], xn1[2], xn2[2];
    xv[0]  = __builtin_nontemporal_load(&xq0[ks]);            // c=0
    xv[1]  = __builtin_nontemporal_load(&xq1[ks]);
    xn1[0] = __builtin_nontemporal_load(&xq0[8 + ks]);        // c=1
    xn1[1] = __builtin_nontemporal_load(&xq1[8 + ks]);

    for (int c = 0; c < 16; c++) {
        if (c < 14) {   // prefetch c+2 (two c-iters of latency cover)
            xn2[0] = __builtin_nontemporal_load(&xq0[(c + 2) * 8 + ks]);
            xn2[1] = __builtin_nontemporal_load(&xq1[(c + 2) * 8 + ks]);
        }
#pragma unroll
        for (int m = 0; m < 4; m++) {
            int k = c * 32 + ks * 4 + m;
            const float* wrow = &Wl[k * 16 + (k >> 2) * 4];
            float4 wv[4];
#pragma unroll
            for (int j4 = 0; j4 < 4; j4++)
                wv[j4] = *reinterpret_cast<const float4*>(wrow + j4 * 4);
#pragma unroll
            for (int rr = 0; rr < 2; rr++) {
                float xs = xv[rr][m];
#pragma unroll
                for (int j4 = 0; j4 < 4; j4++) {
                    acc[rr][j4 * 4 + 0] = fmaf(xs, wv[j4].x, acc[rr][j4 * 4 + 0]);
                    acc[rr][j4 * 4 + 1] = fmaf(xs, wv[j4].y, acc[rr][j4 * 4 + 1]);
                    acc[rr][j4 * 4 + 2] = fmaf(xs, wv[j4].z, acc[rr][j4 * 4 + 2]);
                    acc[rr][j4 * 4 + 3] = fmaf(xs, wv[j4].w, acc[rr][j4 * 4 + 3]);
                }
            }
        }
        xv[0] = xn1[0];
        xv[1] = xn1[1];
        xn1[0] = xn2[0];
        xn1[1] = xn2[1];
    }

#pragma unroll
    for (int off = 1; off < 8; off <<= 1)
#pragma unroll
        for (int rr = 0; rr < 2; rr++)
#pragma unroll
            for (int j = 0; j < 16; j++)
                acc[rr][j] += __shfl_xor(acc[rr][j], off, 8);

    if (ks == 0) {
#pragma unroll
        for (int rr = 0; rr < 2; rr++) {
            int r = rbase + rr;
            if (r < n) {
                float dr = dinv[r];
                uint32 us[8];
#pragma unroll
                for (int q = 0; q < 8; q++) {
                    uint32 lo = f2bf(dr * acc[rr][q * 2]);
                    uint32 hi = f2bf(dr * acc[rr][q * 2 + 1]);
                    us[q] = lo | (hi << 16);
                }
                uint4* o = reinterpret_cast<uint4*>(g1 + (size_t)r * 8);
                o[0] = make_uint4(us[0], us[1], us[2], us[3]);
                o[1] = make_uint4(us[4], us[5], us[6], us[7]);
            }
        }
    }
}

// ---------------- layer 1 aggregation + bias + relu; g2 = bf16(dinv ⊙ relu(z)) ----
// 8 lanes/row, each lane owns a bf16 feature-pair; unroll-16 for deep MLP.
__global__ __launch_bounds__(256) void k_agg1(const uint32* __restrict__ g1,
                                              const int* __restrict__ start,
                                              const int* __restrict__ end,
                                              const int* __restrict__ csr,
                                              const float* __restrict__ dinv,
                                              const float* __restrict__ b1,
                                              uint32* __restrict__ g2, int n) {
    int g = threadIdx.x >> 3;
    int l = threadIdx.x & 7;
    int r = blockIdx.x * 32 + g;
    if (r >= n) return;
    int s = start[r], e = end[r];
    float a0 = 0.f, a1 = 0.f;
    int p = s;
    for (; p + 16 <= e; p += 16) {
        int c[16];
#pragma unroll
        for (int u = 0; u < 16; u++) c[u] = csr[p + u];
        uint32 hv[16];
#pragma unroll
        for (int u = 0; u < 16; u++) hv[u] = g1[c[u] * 8 + l];
#pragma unroll
        for (int u = 0; u < 16; u++) {
            a0 += bf2f(hv[u] & 0xFFFFu);
            a1 += bf2f(hv[u] >> 16);
        }
    }
    for (; p + 8 <= e; p += 8) {
        int c[8];
#pragma unroll
        for (int u = 0; u < 8; u++) c[u] = csr[p + u];
        uint32 hv[8];
#pragma unroll
        for (int u = 0; u < 8; u++) hv[u] = g1[c[u] * 8 + l];
#pragma unroll
        for (int u = 0; u < 8; u++) {
            a0 += bf2f(hv[u] & 0xFFFFu);
            a1 += bf2f(hv[u] >> 16);
        }
    }
    for (; p < e; p++) {
        uint32 h = g1[csr[p] * 8 + l];
        a0 += bf2f(h & 0xFFFFu);
        a1 += bf2f(h >> 16);
    }
    uint32 hs = g1[r * 8 + l];
    float dr = dinv[r];
    float z0 = fmaf(dr, a0 + bf2f(hs & 0xFFFFu), b1[2 * l]);
    float z1 = fmaf(dr, a1 + bf2f(hs >> 16), b1[2 * l + 1]);
    g2[r * 8 + l] = f2bf(dr * fmaxf(z0, 0.f)) | (f2bf(dr * fmaxf(z1, 0.f)) << 16);
}

// ---------------- layer 2 fused: aggregate g2, @W2 + b2 + log_softmax ----------
__global__ __launch_bounds__(256) void k_agg2(const uint32* __restrict__ g2,
                                              const int* __restrict__ start,
                                              const int* __restrict__ end,
                                              const int* __restrict__ csr,
                                              const float* __restrict__ dinv,
                                              const float* __restrict__ W2,
                                              const float* __restrict__ b2,
                                              float* __restrict__ out, int n) {
    __shared__ float vsm[32][17];
    int g = threadIdx.x >> 3;
    int l = threadIdx.x & 7;
    int r = blockIdx.x * 32 + g;
    float a0 = 0.f, a1 = 0.f;
    if (r < n) {
        int s = start[r], e = end[r];
        int p = s;
        for (; p + 16 <= e; p += 16) {
            int c[16];
#pragma unroll
            for (int u = 0; u < 16; u++) c[u] = csr[p + u];
            uint32 hv[16];
#pragma unroll
            for (int u = 0; u < 16; u++) hv[u] = g2[c[u] * 8 + l];
#pragma unroll
            for (int u = 0; u < 16; u++) {
                a0 += bf2f(hv[u] & 0xFFFFu);
                a1 += bf2f(hv[u] >> 16);
            }
        }
        for (; p + 8 <= e; p += 8) {
            int c[8];
#pragma unroll
            for (int u = 0; u < 8; u++) c[u] = csr[p + u];
            uint32 hv[8];
#pragma unroll
            for (int u = 0; u < 8; u++) hv[u] = g2[c[u] * 8 + l];
#pragma unroll
            for (int u = 0; u < 8; u++) {
                a0 += bf2f(hv[u] & 0xFFFFu);
                a1 += bf2f(hv[u] >> 16);
            }
        }
        for (; p < e; p++) {
            uint32 h = g2[csr[p] * 8 + l];
            a0 += bf2f(h & 0xFFFFu);
            a1 += bf2f(h >> 16);
        }
        uint32 hs = g2[r * 8 + l];
        float dr = dinv[r];
        a0 = dr * (a0 + bf2f(hs & 0xFFFFu));
        a1 = dr * (a1 + bf2f(hs >> 16));
    }
    vsm[g][2 * l] = a0;
    vsm[g][2 * l + 1] = a1;
    __syncthreads();
    if (r >= n) return;

    float vloc[16];
#pragma unroll
    for (int k = 0; k < 16; k++) vloc[k] = vsm[g][k];

    float z[5];
#pragma unroll
    for (int i = 0; i < 5; i++) z[i] = b2[l + 8 * i];
#pragma unroll
    for (int k = 0; k < 16; k++) {
        float vk = vloc[k];
        const float* wk = W2 + k * NCLS;
#pragma unroll
        for (int i = 0; i < 5; i++) z[i] = fmaf(vk, wk[l + 8 * i], z[i]);
    }
    float m = z[0];
#pragma unroll
    for (int i = 1; i < 5; i++) m = fmaxf(m, z[i]);
#pragma unroll
    for (int off = 1; off < 8; off <<= 1) m = fmaxf(m, __shfl_xor(m, off, 8));
    float ssum = 0.f;
#pragma unroll
    for (int i = 0; i < 5; i++) ssum += __expf(z[i] - m);
#pragma unroll
    for (int off = 1; off < 8; off <<= 1) ssum += __shfl_xor(ssum, off, 8);
    float ls = m + logf(ssum);
    float* o = out + (size_t)r * NCLS;
#pragma unroll
    for (int i = 0; i < 5; i++) o[l + 8 * i] = z[i] - ls;
}

// ---------------- launch ----------------

extern "C" void kernel_launch(void* const* d_in, const int* in_sizes, int n_in,
                              void* d_out, int out_size, void* d_ws, size_t ws_size,
                              hipStream_t stream) {
    const float* x  = (const float*)d_in[0];
    const int*   ei = (const int*)d_in[1];
    const float* W1 = (const float*)d_in[2];
    const float* b1 = (const float*)d_in[3];
    const float* W2 = (const float*)d_in[4];
    const float* b2 = (const float*)d_in[5];

    const int n = in_sizes[0] / NFEAT;   // 100000
    const int E = in_sizes[1] / 2;       // 3200000
    const int* row = ei;
    const int* col = ei + E;
    const int nb = (n + BROWS - 1) / BROWS;   // 391

    char* w = (char*)d_ws;
    auto alloc = [&](size_t bytes) {
        void* p = (void*)w;
        w += (bytes + 255) & ~(size_t)255;
        return p;
    };
    int*    start = (int*)alloc((size_t)n * 4);
    int*    end   = (int*)alloc((size_t)n * 4);
    int*    cnt   = (int*)alloc((size_t)n * 4);
    int*    bcur  = (int*)alloc(2048);
    float*  dinv  = (float*)alloc((size_t)n * 4);
    int*    csr   = (int*)alloc((size_t)nb * BCAP * 4);
    uint32* pairs = (uint32*)alloc((size_t)nb * BCAP * 4);
    uint32* g1    = (uint32*)alloc((size_t)n * HID * 2);
    uint32* g2    = (uint32*)alloc((size_t)n * HID * 2);

    hipMemsetAsync(bcur, 0, 2048, stream);
    k_pairs<<<512, 256, 0, stream>>>(row, col, bcur, pairs, E, nb);
    k_deg<<<nb, 256, 0, stream>>>(bcur, pairs, cnt, dinv, n);
    k_fused<<<nb + (n + 63) / 64, 256, 0, stream>>>(bcur, pairs, cnt, csr, start, end,
                                                    x, W1, dinv, g1, n, nb);
    k_agg1<<<(n + 31) / 32, 256, 0, stream>>>(g1, start, end, csr, dinv, b1, g2, n);
    k_agg2<<<(n + 31) / 32, 256, 0, stream>>>(g2, start, end, csr, dinv, W2, b2,
                                              (float*)d_out, n);
}